// Round 3
// baseline (430.087 us; speedup 1.0000x reference)
//
#include <hip/hip_runtime.h>
#include <hip/hip_bf16.h>
#include <cstdint>

using u16 = unsigned short;
typedef __attribute__((ext_vector_type(8))) short bf16x8;
typedef __attribute__((ext_vector_type(4))) float f32x4;
typedef __attribute__((ext_vector_type(4))) u16 u16x4;

#define MFMA_BF16(a, b, c) __builtin_amdgcn_mfma_f32_16x16x32_bf16((a), (b), (c), 0, 0, 0)

__device__ __forceinline__ u16 f2bf(float f) {
  __hip_bfloat16 h = __float2bfloat16(f);
  return __builtin_bit_cast(u16, h);
}

__device__ __forceinline__ void gl_lds16(const void* gsrc, void* ldst) {
  __builtin_amdgcn_global_load_lds(
      (__attribute__((address_space(1))) void*)const_cast<void*>(gsrc),
      (__attribute__((address_space(3))) void*)ldst, 16, 0, 0);
}

// ---------------------------------------------------------------- transpose+convert: src [K][N] f32 -> dst [N][K] bf16
__global__ __launch_bounds__(256) void transpose_conv(const float* __restrict__ src,
                                                      u16* __restrict__ dst, int K, int N) {
  __shared__ float t[32][33];
  const int bx = blockIdx.x, by = blockIdx.y;  // bx: N/32, by: K/32
  const int tid = threadIdx.x;
  const int r = tid >> 3, c = (tid & 7) * 4;
  const float4 v = *(const float4*)&src[(size_t)(by * 32 + r) * N + bx * 32 + c];
  t[r][c] = v.x; t[r][c + 1] = v.y; t[r][c + 2] = v.z; t[r][c + 3] = v.w;
  __syncthreads();
  u16x4 o;
  o.x = f2bf(t[c][r]); o.y = f2bf(t[c + 1][r]); o.z = f2bf(t[c + 2][r]); o.w = f2bf(t[c + 3][r]);
  *(u16x4*)&dst[(size_t)(bx * 32 + r) * K + by * 32 + c] = o;
}

// ---------------------------------------------------------------- V^T extraction: qkv [8192][3072] -> vt [128][64][1024]
__global__ __launch_bounds__(256) void transpose_v(const u16* __restrict__ qkv, u16* __restrict__ dst) {
  __shared__ u16 t[32][40];
  const int bx = blockIdx.x;  // d-block: 0..1
  const int by = blockIdx.y;  // n-block: 0..31
  const int bh = blockIdx.z;  // 0..127
  const int b = bh >> 4, h = bh & 15;
  const int tid = threadIdx.x;
  const int r = tid >> 3, c = (tid & 7) * 4;
  u16x4 v = *(const u16x4*)&qkv[(size_t)(b * 1024 + by * 32 + r) * 3072 + 2048 + h * 64 + bx * 32 + c];
  t[r][c] = v.x; t[r][c + 1] = v.y; t[r][c + 2] = v.z; t[r][c + 3] = v.w;
  __syncthreads();
  u16x4 o = {t[c][r], t[c + 1][r], t[c + 2][r], t[c + 3][r]};
  *(u16x4*)&dst[(size_t)bh * 65536 + (size_t)(bx * 32 + r) * 1024 + by * 32 + c] = o;
}

// ---------------------------------------------------------------- LayerNorm: x f32 [8192][1024] -> bf16 out
__global__ __launch_bounds__(256) void ln_kernel(const float* __restrict__ x, const float* __restrict__ g,
                                                 const float* __restrict__ b, u16* __restrict__ out) {
  const int row = blockIdx.x, tid = threadIdx.x;
  const float* xr = x + (size_t)row * 1024;
  float4 v = *(const float4*)&xr[tid * 4];
  float s = v.x + v.y + v.z + v.w;
  float s2 = v.x * v.x + v.y * v.y + v.z * v.z + v.w * v.w;
#pragma unroll
  for (int off = 32; off; off >>= 1) { s += __shfl_xor(s, off); s2 += __shfl_xor(s2, off); }
  __shared__ float ps[4], ps2[4];
  const int wave = tid >> 6;
  if ((tid & 63) == 0) { ps[wave] = s; ps2[wave] = s2; }
  __syncthreads();
  s = ps[0] + ps[1] + ps[2] + ps[3];
  s2 = ps2[0] + ps2[1] + ps2[2] + ps2[3];
  const float mu = s * (1.0f / 1024.0f);
  const float var = s2 * (1.0f / 1024.0f) - mu * mu;
  const float rs = rsqrtf(var + 1e-5f);
  float4 gv = *(const float4*)&g[tid * 4];
  float4 bv = *(const float4*)&b[tid * 4];
  u16x4 o;
  o.x = f2bf((v.x - mu) * rs * gv.x + bv.x);
  o.y = f2bf((v.y - mu) * rs * gv.y + bv.y);
  o.z = f2bf((v.z - mu) * rs * gv.z + bv.z);
  o.w = f2bf((v.w - mu) * rs * gv.w + bv.w);
  *(u16x4*)&out[(size_t)row * 1024 + tid * 4] = o;
}

// ---------------------------------------------------------------- 8-phase 256x256 GEMM (T2+T3+T4+T5)
// C[M][N] = A[M][K] * Bt[N][K]^T, BK=64, 512 threads = 8 waves (2M x 4N),
// LDS 128 KiB: [buf 2][mat A/B][half 2][128 rows][64 k], chunk-swizzled
// phys_chunk = log_chunk ^ (row&7). Staging via global_load_lds with the
// inverse swizzle applied to the per-lane GLOBAL source chunk.
// Phases per K-tile t: p0{read A-half0 + B-lo, stage B0(t+1)->nxt},
// p1{read A-half1 + B-hi, stage B1(t+1)->nxt}, p2{stage A0(t+2)->cur},
// p3{reload B-lo, stage A1(t+2)->cur, vmcnt(4)}. Counted vmcnt: the 4
// newest outstanding loads at p3 are A(t+2); all of tile t+1 has landed.
template <int EPI>
__global__ __launch_bounds__(512, 2) void gemm8p(const u16* __restrict__ A, const u16* __restrict__ Bt,
                                                 const float* __restrict__ bias, const float* __restrict__ xres,
                                                 const float* __restrict__ ls, float* __restrict__ outf,
                                                 u16* __restrict__ outh, int M, int N, int K) {
  __shared__ __attribute__((aligned(16))) u16 S[65536];  // 128 KiB
  const int tid = threadIdx.x;
  const int w = tid >> 6, l = tid & 63;
  const int wr = w >> 2, wc = w & 3;
  const int fr = l & 15, fq = l >> 4;
  const int bm = blockIdx.x, bn = blockIdx.y;
  const int nt = K >> 6;

  // per-thread ds_read offsets (elems): row fr within 16-row frag, k-chunk (kk*4+fq)^(l&7)
  const int off0 = fr * 64 + ((fq ^ (l & 7)) * 8);
  const int off1 = off0 ^ 32;  // chunk xor 4

  // staging: lane covers phys slot row = i*64 + w*8 + (l>>3), chunk l&7 -> src chunk (l&7)^(l>>3)
  const int srow = w * 8 + (l >> 3);
  const int schunk = ((l & 7) ^ (l >> 3)) * 8;
  const u16* Ag = A + (size_t)(bm * 256 + srow) * K + schunk;
  const u16* Bg = Bt + (size_t)(bn * 256 + srow) * K + schunk;
  u16* sbase = &S[w * 512];
  const size_t rowK64 = (size_t)64 * K;
  const size_t rowK128 = (size_t)128 * K;

  f32x4 acc[8][4];
  f32x4 zero = {0.f, 0.f, 0.f, 0.f};
#pragma unroll
  for (int i = 0; i < 8; i++)
#pragma unroll
    for (int j = 0; j < 4; j++) acc[i][j] = zero;

#define STAGE8(mat, h, tk, b)                                                      \
  do {                                                                             \
    const u16* g_ = ((mat) ? Bg : Ag) + (size_t)(h)*rowK128 + (size_t)(tk) * 64;   \
    u16* d_ = sbase + (((b)*2 + (mat)) * 2 + (h)) * 8192;                          \
    gl_lds16(g_, d_);                                                              \
    gl_lds16(g_ + rowK64, d_ + 4096);                                              \
  } while (0)

  // prologue: tile0 fully + A halves of tile1
  STAGE8(0, 0, 0, 0); STAGE8(0, 1, 0, 0); STAGE8(1, 0, 0, 0); STAGE8(1, 1, 0, 0);
  STAGE8(0, 0, 1, 1); STAGE8(0, 1, 1, 1);
  asm volatile("s_waitcnt vmcnt(4)" ::: "memory");
  __builtin_amdgcn_s_barrier();

  for (int t = 0; t < nt; ++t) {
    const int cur = t & 1, nxt = cur ^ 1;
    const int tp1 = (t + 1 < nt) ? t + 1 : t + 1 - nt;
    const int tp2 = (t + 2 < nt) ? t + 2 : t + 2 - nt;
    const int rA = cur * 32768 + wr * 8192;
    const int rB = cur * 32768 + 16384 + (wc >> 1) * 8192 + (wc & 1) * 4096;
    bf16x8 a0[4][2], a1[4][2], bA[2][2], bB[2][2];

    // ---- phase 0: A rows 0-63 + B cols 0-31; stage B0(t+1)
#pragma unroll
    for (int mi = 0; mi < 4; mi++) {
      a0[mi][0] = *(const bf16x8*)&S[rA + mi * 1024 + off0];
      a0[mi][1] = *(const bf16x8*)&S[rA + mi * 1024 + off1];
    }
#pragma unroll
    for (int ni = 0; ni < 2; ni++) {
      bA[ni][0] = *(const bf16x8*)&S[rB + ni * 1024 + off0];
      bA[ni][1] = *(const bf16x8*)&S[rB + ni * 1024 + off1];
    }
    STAGE8(1, 0, tp1, nxt);
    __builtin_amdgcn_s_barrier();
    asm volatile("s_waitcnt lgkmcnt(0)" ::: "memory");
    __builtin_amdgcn_s_setprio(1);
#pragma unroll
    for (int mi = 0; mi < 4; mi++)
#pragma unroll
      for (int ni = 0; ni < 2; ni++) {
        acc[mi][ni] = MFMA_BF16(a0[mi][0], bA[ni][0], acc[mi][ni]);
        acc[mi][ni] = MFMA_BF16(a0[mi][1], bA[ni][1], acc[mi][ni]);
      }
    __builtin_amdgcn_s_setprio(0);
    __builtin_amdgcn_s_barrier();

    // ---- phase 1: A rows 64-127 + B cols 32-63; stage B1(t+1)
#pragma unroll
    for (int mi = 0; mi < 4; mi++) {
      a1[mi][0] = *(const bf16x8*)&S[rA + (mi + 4) * 1024 + off0];
      a1[mi][1] = *(const bf16x8*)&S[rA + (mi + 4) * 1024 + off1];
    }
#pragma unroll
    for (int ni = 0; ni < 2; ni++) {
      bB[ni][0] = *(const bf16x8*)&S[rB + (ni + 2) * 1024 + off0];
      bB[ni][1] = *(const bf16x8*)&S[rB + (ni + 2) * 1024 + off1];
    }
    STAGE8(1, 1, tp1, nxt);
    __builtin_amdgcn_s_barrier();
    asm volatile("s_waitcnt lgkmcnt(0)" ::: "memory");
    __builtin_amdgcn_s_setprio(1);
#pragma unroll
    for (int mi = 0; mi < 4; mi++)
#pragma unroll
      for (int ni = 0; ni < 2; ni++) {
        acc[mi + 4][ni + 2] = MFMA_BF16(a1[mi][0], bB[ni][0], acc[mi + 4][ni + 2]);
        acc[mi + 4][ni + 2] = MFMA_BF16(a1[mi][1], bB[ni][1], acc[mi + 4][ni + 2]);
      }
    __builtin_amdgcn_s_setprio(0);
    __builtin_amdgcn_s_barrier();

    // ---- phase 2: (A0 x B-hi) from regs; stage A0(t+2) into cur (A reads done)
    STAGE8(0, 0, tp2, cur);
    __builtin_amdgcn_s_barrier();
    __builtin_amdgcn_s_setprio(1);
#pragma unroll
    for (int mi = 0; mi < 4; mi++)
#pragma unroll
      for (int ni = 0; ni < 2; ni++) {
        acc[mi][ni + 2] = MFMA_BF16(a0[mi][0], bB[ni][0], acc[mi][ni + 2]);
        acc[mi][ni + 2] = MFMA_BF16(a0[mi][1], bB[ni][1], acc[mi][ni + 2]);
      }
    __builtin_amdgcn_s_setprio(0);
    __builtin_amdgcn_s_barrier();

    // ---- phase 3: reload B-lo; (A1 x B-lo); stage A1(t+2); counted vmcnt
#pragma unroll
    for (int ni = 0; ni < 2; ni++) {
      bA[ni][0] = *(const bf16x8*)&S[rB + ni * 1024 + off0];
      bA[ni][1] = *(const bf16x8*)&S[rB + ni * 1024 + off1];
    }
    STAGE8(0, 1, tp2, cur);
    asm volatile("s_waitcnt vmcnt(4)" ::: "memory");
    __builtin_amdgcn_s_barrier();
    asm volatile("s_waitcnt lgkmcnt(0)" ::: "memory");
    __builtin_amdgcn_s_setprio(1);
#pragma unroll
    for (int mi = 0; mi < 4; mi++)
#pragma unroll
      for (int ni = 0; ni < 2; ni++) {
        acc[mi + 4][ni] = MFMA_BF16(a1[mi][0], bA[ni][0], acc[mi + 4][ni]);
        acc[mi + 4][ni] = MFMA_BF16(a1[mi][1], bA[ni][1], acc[mi + 4][ni]);
      }
    __builtin_amdgcn_s_setprio(0);
    __builtin_amdgcn_s_barrier();
  }
#undef STAGE8

  // epilogue
  const int row0 = bm * 256 + wr * 128;
  const int col0 = bn * 256 + wc * 64;
#pragma unroll
  for (int mi = 0; mi < 8; mi++)
#pragma unroll
    for (int ni = 0; ni < 4; ni++)
#pragma unroll
      for (int j = 0; j < 4; j++) {
        const int r = row0 + mi * 16 + fq * 4 + j;
        const int c = col0 + ni * 16 + fr;
        float v = acc[mi][ni][j];
        if constexpr (EPI == 0) {
          outh[(size_t)r * N + c] = f2bf(v + bias[c]);
        } else if constexpr (EPI == 1) {
          const size_t idx = (size_t)r * N + c;
          outf[idx] = xres[idx] + ls[c] * (v + bias[c]);
        } else if constexpr (EPI == 2) {
          v += bias[c];
          outh[(size_t)r * N + c] = f2bf(0.5f * v * (1.0f + erff(v * 0.70710678118654752f)));
        } else {
          const size_t idx = (size_t)r * N + c;
          outf[idx] += ls[c] * (v + bias[c]);
        }
      }
}

// ---------------------------------------------------------------- 128x128 GEMM (proj, FC2) with chunk swizzle
// LDS rows 32 elems = 4 chunks; phys_chunk = log ^ ((row>>1)&3) -> 2-way conflicts.
template <int EPI>
__global__ __launch_bounds__(256, 2) void gemm_bt(const u16* __restrict__ A, const u16* __restrict__ Bt,
                                                  const float* __restrict__ bias, const float* __restrict__ xres,
                                                  const float* __restrict__ ls, float* __restrict__ outf,
                                                  u16* __restrict__ outh, int M, int N, int K) {
  __shared__ __attribute__((aligned(16))) u16 As[128 * 32];
  __shared__ __attribute__((aligned(16))) u16 Bs[128 * 32];
  const int tid = threadIdx.x;
  const int wave = tid >> 6, lane = tid & 63;
  const int lrow = lane & 15, lhi = lane >> 4;
  const int bm = blockIdx.x, bn = blockIdx.y;
  const int wr = wave >> 1, wc = wave & 1;

  f32x4 zero = {0.f, 0.f, 0.f, 0.f};
  f32x4 acc[4][4];
#pragma unroll
  for (int i = 0; i < 4; i++)
#pragma unroll
    for (int j = 0; j < 4; j++) acc[i][j] = zero;

  // stage: dest row = wave*16 + (lane>>2), chunk lane&3; src chunk = (lane&3)^((lane>>3)&3)
  const int schunk = ((lane & 3) ^ ((lane >> 3) & 3)) * 8;
  const u16* Abase = A + (size_t)(bm * 128 + wave * 16 + (lane >> 2)) * K + schunk;
  const u16* Bbase = Bt + (size_t)(bn * 128 + wave * 16 + (lane >> 2)) * K + schunk;
  u16* AsW0 = &As[(wave * 16) * 32];
  u16* AsW1 = &As[(64 + wave * 16) * 32];
  u16* BsW0 = &Bs[(wave * 16) * 32];
  u16* BsW1 = &Bs[(64 + wave * 16) * 32];
  const size_t rowK64 = (size_t)64 * K;
  // read: phys chunk = lhi ^ ((lrow>>1)&3)
  const int rchunk = (lhi ^ ((lrow >> 1) & 3)) * 8;

  for (int kt = 0; kt < K; kt += 32) {
    __syncthreads();
    gl_lds16(Abase + kt, AsW0);
    gl_lds16(Abase + rowK64 + kt, AsW1);
    gl_lds16(Bbase + kt, BsW0);
    gl_lds16(Bbase + rowK64 + kt, BsW1);
    __syncthreads();
    bf16x8 af[4], bfr[4];
#pragma unroll
    for (int mi = 0; mi < 4; mi++) af[mi] = *(const bf16x8*)&As[(wr * 64 + mi * 16 + lrow) * 32 + rchunk];
#pragma unroll
    for (int ni = 0; ni < 4; ni++) bfr[ni] = *(const bf16x8*)&Bs[(wc * 64 + ni * 16 + lrow) * 32 + rchunk];
#pragma unroll
    for (int mi = 0; mi < 4; mi++)
#pragma unroll
      for (int ni = 0; ni < 4; ni++) acc[mi][ni] = MFMA_BF16(af[mi], bfr[ni], acc[mi][ni]);
  }

  const int row0 = bm * 128 + wr * 64;
  const int col0 = bn * 128 + wc * 64;
#pragma unroll
  for (int mi = 0; mi < 4; mi++) {
#pragma unroll
    for (int ni = 0; ni < 4; ni++) {
#pragma unroll
      for (int i = 0; i < 4; i++) {
        const int r = row0 + mi * 16 + lhi * 4 + i;
        const int c = col0 + ni * 16 + lrow;
        float v = acc[mi][ni][i];
        if constexpr (EPI == 0) {
          outh[(size_t)r * N + c] = f2bf(v + bias[c]);
        } else if constexpr (EPI == 1) {
          const size_t idx = (size_t)r * N + c;
          outf[idx] = xres[idx] + ls[c] * (v + bias[c]);
        } else if constexpr (EPI == 2) {
          v += bias[c];
          outh[(size_t)r * N + c] = f2bf(0.5f * v * (1.0f + erff(v * 0.70710678118654752f)));
        } else {
          const size_t idx = (size_t)r * N + c;
          outf[idx] += ls[c] * (v + bias[c]);
        }
      }
    }
  }
}

// ---------------------------------------------------------------- flash attention (T2-swizzled LDS)
__global__ __launch_bounds__(256, 3) void attn_kernel(const u16* __restrict__ qkv, const u16* __restrict__ vt,
                                                      u16* __restrict__ o) {
  __shared__ __attribute__((aligned(16))) u16 Ks[128 * 64];
  __shared__ __attribute__((aligned(16))) u16 Vs[64 * 128];
  __shared__ __attribute__((aligned(16))) u16 PQ[4 * 16 * 128];
  u16* Qs = PQ;
  const int tid = threadIdx.x;
  const int wave = tid >> 6, lane = tid & 63;
  const int lrow = lane & 15, lhi = lane >> 4;
  const int qt = blockIdx.x;
  const int bh = blockIdx.y;
  const int b = bh >> 4, h = bh & 15;
  const int swz8 = (lane & 7) ^ (lane >> 3);
  const int swz16 = (lane & 15) ^ (wave * 4 + (lane >> 4));

  {
    const u16* gq = qkv + (size_t)(b * 1024 + qt * 64 + wave * 8 + (lane >> 3)) * 3072 + h * 64 + swz8 * 8;
    gl_lds16(gq, &Qs[(wave * 8) * 64]);
    gl_lds16(gq + (size_t)32 * 3072, &Qs[(32 + wave * 8) * 64]);
  }
  __syncthreads();
  const int pq0 = (lhi ^ (lrow & 7)) * 8;
  bf16x8 qf0 = *(const bf16x8*)&Qs[(wave * 16 + lrow) * 64 + pq0];
  bf16x8 qf1 = *(const bf16x8*)&Qs[(wave * 16 + lrow) * 64 + (pq0 ^ 32)];

  float m_[4], l_[4];
  f32x4 oa[4];
  f32x4 zero = {0.f, 0.f, 0.f, 0.f};
#pragma unroll
  for (int i = 0; i < 4; i++) { m_[i] = -1e30f; l_[i] = 0.f; oa[i] = zero; }

  const u16* kg = qkv + (size_t)(b * 1024 + wave * 8 + (lane >> 3)) * 3072 + 1024 + h * 64 + swz8 * 8;
  const u16* vg = vt + (size_t)bh * 65536 + (size_t)(wave * 4 + (lane >> 4)) * 1024 + swz16 * 8;

  for (int kt = 0; kt < 1024; kt += 128) {
    __syncthreads();
#pragma unroll
    for (int i = 0; i < 4; i++) gl_lds16(kg + (size_t)(kt + i * 32) * 3072, &Ks[(i * 32 + wave * 8) * 64]);
#pragma unroll
    for (int i = 0; i < 4; i++) gl_lds16(vg + (size_t)(i * 16) * 1024 + kt, &Vs[(i * 16 + wave * 4) * 128]);
    __syncthreads();

    f32x4 sf[8];
#pragma unroll
    for (int n = 0; n < 8; n++) sf[n] = zero;
#pragma unroll
    for (int n = 0; n < 8; n++) {
      bf16x8 kf0 = *(const bf16x8*)&Ks[(n * 16 + lrow) * 64 + pq0];
      bf16x8 kf1 = *(const bf16x8*)&Ks[(n * 16 + lrow) * 64 + (pq0 ^ 32)];
      sf[n] = MFMA_BF16(qf0, kf0, sf[n]);
      sf[n] = MFMA_BF16(qf1, kf1, sf[n]);
    }

    float tm[4] = {-1e30f, -1e30f, -1e30f, -1e30f};
#pragma unroll
    for (int n = 0; n < 8; n++)
#pragma unroll
      for (int i = 0; i < 4; i++) tm[i] = fmaxf(tm[i], sf[n][i]);
#pragma unroll
    for (int i = 0; i < 4; i++) tm[i] *= 0.125f;
#pragma unroll
    for (int off = 1; off < 16; off <<= 1)
#pragma unroll
      for (int i = 0; i < 4; i++) tm[i] = fmaxf(tm[i], __shfl_xor(tm[i], off));
    float al[4];
#pragma unroll
    for (int i = 0; i < 4; i++) {
      const float mn = fmaxf(m_[i], tm[i]);
      al[i] = __expf(m_[i] - mn);
      m_[i] = mn;
    }
    float rs[4] = {0.f, 0.f, 0.f, 0.f};
#pragma unroll
    for (int n = 0; n < 8; n++)
#pragma unroll
      for (int i = 0; i < 4; i++) {
        const float p = __expf(sf[n][i] * 0.125f - m_[i]);
        rs[i] += p;
        const int q = lhi * 4 + i;
        PQ[wave * 2048 + q * 128 + (((n * 2 + (lrow >> 3)) ^ q) * 8) + (lrow & 7)] = f2bf(p);
      }
#pragma unroll
    for (int off = 1; off < 16; off <<= 1)
#pragma unroll
      for (int i = 0; i < 4; i++) rs[i] += __shfl_xor(rs[i], off);
#pragma unroll
    for (int i = 0; i < 4; i++) l_[i] = l_[i] * al[i] + rs[i];
#pragma unroll
    for (int n2 = 0; n2 < 4; n2++)
#pragma unroll
      for (int i = 0; i < 4; i++) oa[n2][i] *= al[i];

#pragma unroll
    for (int ks = 0; ks < 4; ks++) {
      bf16x8 pf = *(const bf16x8*)&PQ[wave * 2048 + lrow * 128 + (((ks * 4 + lhi) ^ lrow) * 8)];
#pragma unroll
      for (int n2 = 0; n2 < 4; n2++) {
        bf16x8 vf = *(const bf16x8*)&Vs[(n2 * 16 + lrow) * 128 + (((ks * 4 + lhi) ^ lrow) * 8)];
        oa[n2] = MFMA_BF16(pf, vf, oa[n2]);
      }
    }
  }

#pragma unroll
  for (int n2 = 0; n2 < 4; n2++)
#pragma unroll
    for (int i = 0; i < 4; i++) {
      const int tok = qt * 64 + wave * 16 + lhi * 4 + i;
      o[(size_t)(b * 1024 + tok) * 1024 + h * 64 + n2 * 16 + lrow] = f2bf(oa[n2][i] / l_[i]);
    }
}

// ----------------------------------------------------------------
extern "C" void kernel_launch(void* const* d_in, const int* in_sizes, int n_in, void* d_out, int out_size,
                              void* d_ws, size_t ws_size, hipStream_t stream) {
  const float* x = (const float*)d_in[0];
  const float* ln1_g = (const float*)d_in[1];
  const float* ln1_b = (const float*)d_in[2];
  const float* qkv_w = (const float*)d_in[3];
  const float* qkv_b = (const float*)d_in[4];
  const float* proj_w = (const float*)d_in[5];
  const float* proj_b = (const float*)d_in[6];
  const float* ls1_g = (const float*)d_in[7];
  const float* ln2_g = (const float*)d_in[8];
  const float* ln2_b = (const float*)d_in[9];
  const float* fc1_w = (const float*)d_in[10];
  const float* fc1_b = (const float*)d_in[11];
  const float* fc2_w = (const float*)d_in[12];
  const float* fc2_b = (const float*)d_in[13];
  const float* ls2_g = (const float*)d_in[14];
  float* out = (float*)d_out;

  u16* w = (u16*)d_ws;
  u16* wq = w;                          // [3072][1024]
  u16* wp = wq + (size_t)3072 * 1024;   // [1024][1024]
  u16* wf1 = wp + (size_t)1024 * 1024;  // [4096][1024]
  u16* wf2 = wf1 + (size_t)4096 * 1024; // [1024][4096]
  u16* hbuf = wf2 + (size_t)1024 * 4096;  // [8192][1024]
  u16* qkvb = hbuf + (size_t)8192 * 1024; // [8192][3072]
  u16* vtb = qkvb + (size_t)8192 * 3072;  // [128][64][1024]
  u16* ob = vtb + (size_t)128 * 64 * 1024; // [8192][1024]
  u16* hid = qkvb;  // [8192][4096] aliases qkv+vtb (both dead by FC1)

  // weight transposes (fp32 -> bf16, [K][N] -> [N][K])
  transpose_conv<<<dim3(96, 32), 256, 0, stream>>>(qkv_w, wq, 1024, 3072);
  transpose_conv<<<dim3(32, 32), 256, 0, stream>>>(proj_w, wp, 1024, 1024);
  transpose_conv<<<dim3(128, 32), 256, 0, stream>>>(fc1_w, wf1, 1024, 4096);
  transpose_conv<<<dim3(32, 128), 256, 0, stream>>>(fc2_w, wf2, 4096, 1024);

  // LN1
  ln_kernel<<<8192, 256, 0, stream>>>(x, ln1_g, ln1_b, hbuf);
  // QKV (8-phase 256^2)
  gemm8p<0><<<dim3(32, 12), 512, 0, stream>>>(hbuf, wq, qkv_b, nullptr, nullptr, nullptr, qkvb, 8192, 3072, 1024);
  // V^T extraction
  transpose_v<<<dim3(2, 32, 128), 256, 0, stream>>>(qkvb, vtb);
  // attention
  attn_kernel<<<dim3(16, 128), 256, 0, stream>>>(qkvb, vtb, ob);
  // proj + residual1 -> d_out (fp32 x2)
  gemm_bt<1><<<dim3(64, 8), 256, 0, stream>>>(ob, wp, proj_b, x, ls1_g, out, nullptr, 8192, 1024, 1024);
  // LN2
  ln_kernel<<<8192, 256, 0, stream>>>(out, ln2_g, ln2_b, hbuf);
  // FC1 + GELU (8-phase 256^2)
  gemm8p<2><<<dim3(32, 16), 512, 0, stream>>>(hbuf, wf1, fc1_b, nullptr, nullptr, nullptr, hid, 8192, 4096, 1024);
  // FC2 + residual2 (RMW on d_out)
  gemm_bt<3><<<dim3(64, 8), 256, 0, stream>>>(hid, wf2, fc2_b, nullptr, ls2_g, out, nullptr, 8192, 1024, 4096);
}

// Round 4
// 302.860 us; speedup vs baseline: 1.4201x; 1.4201x over previous
//
#include <hip/hip_runtime.h>
#include <hip/hip_bf16.h>
#include <cstdint>

using u16 = unsigned short;
using u8 = unsigned char;
typedef __attribute__((ext_vector_type(8))) short bf16x8;
typedef __attribute__((ext_vector_type(4))) float f32x4;
typedef __attribute__((ext_vector_type(16))) float f32x16;
typedef __attribute__((ext_vector_type(8))) int i32x8;
typedef __attribute__((ext_vector_type(4))) u16 u16x4;

#define MFMA_BF16(a, b, c) __builtin_amdgcn_mfma_f32_16x16x32_bf16((a), (b), (c), 0, 0, 0)
// MX-scaled fp8 MFMA, unit scales (e8m0 0x7F = 2^0): (a,b,c,cbsz=fp8,blgp=fp8,opA,scaleA,opB,scaleB)
#define MFMA_FP8(a, b, c) \
  __builtin_amdgcn_mfma_scale_f32_32x32x64_f8f6f4((a), (b), (c), 0, 0, 0, 0x7f7f7f7f, 0, 0x7f7f7f7f)

__device__ __forceinline__ u16 f2bf(float f) {
  __hip_bfloat16 h = __float2bfloat16(f);
  return __builtin_bit_cast(u16, h);
}

__device__ __forceinline__ u8 f2fp8(float a) {
  int r = __builtin_amdgcn_cvt_pk_fp8_f32(a, a, 0, false);
  return (u8)(r & 0xff);
}

__device__ __forceinline__ uint32_t f2fp8x4(float a, float b, float c, float d) {
  int r = __builtin_amdgcn_cvt_pk_fp8_f32(a, b, 0, false);
  r = __builtin_amdgcn_cvt_pk_fp8_f32(c, d, r, true);
  return (uint32_t)r;
}

__device__ __forceinline__ void gl_lds16(const void* gsrc, void* ldst) {
  __builtin_amdgcn_global_load_lds(
      (__attribute__((address_space(1))) void*)const_cast<void*>(gsrc),
      (__attribute__((address_space(3))) void*)ldst, 16, 0, 0);
}

// ---------------------------------------------------------------- transpose+convert: src [K][N] f32 -> dst [N][K] fp8
__global__ __launch_bounds__(256) void transpose_conv8(const float* __restrict__ src,
                                                       u8* __restrict__ dst, int K, int N) {
  __shared__ float t[32][33];
  const int bx = blockIdx.x, by = blockIdx.y;  // bx: N/32, by: K/32
  const int tid = threadIdx.x;
  const int r = tid >> 3, c = (tid & 7) * 4;
  const float4 v = *(const float4*)&src[(size_t)(by * 32 + r) * N + bx * 32 + c];
  t[r][c] = v.x; t[r][c + 1] = v.y; t[r][c + 2] = v.z; t[r][c + 3] = v.w;
  __syncthreads();
  uint32_t o = f2fp8x4(t[c][r], t[c + 1][r], t[c + 2][r], t[c + 3][r]);
  *(uint32_t*)&dst[(size_t)(bx * 32 + r) * K + by * 32 + c] = o;
}

// ---------------------------------------------------------------- V^T extraction: qkv [8192][3072] bf16 -> vt [128][64][1024] bf16
__global__ __launch_bounds__(256) void transpose_v(const u16* __restrict__ qkv, u16* __restrict__ dst) {
  __shared__ u16 t[32][40];
  const int bx = blockIdx.x;  // d-block: 0..1
  const int by = blockIdx.y;  // n-block: 0..31
  const int bh = blockIdx.z;  // 0..127
  const int b = bh >> 4, h = bh & 15;
  const int tid = threadIdx.x;
  const int r = tid >> 3, c = (tid & 7) * 4;
  u16x4 v = *(const u16x4*)&qkv[(size_t)(b * 1024 + by * 32 + r) * 3072 + 2048 + h * 64 + bx * 32 + c];
  t[r][c] = v.x; t[r][c + 1] = v.y; t[r][c + 2] = v.z; t[r][c + 3] = v.w;
  __syncthreads();
  u16x4 o = {t[c][r], t[c + 1][r], t[c + 2][r], t[c + 3][r]};
  *(u16x4*)&dst[(size_t)bh * 65536 + (size_t)(bx * 32 + r) * 1024 + by * 32 + c] = o;
}

// ---------------------------------------------------------------- LayerNorm: x f32 [8192][1024] -> fp8 out
__global__ __launch_bounds__(256) void ln_kernel(const float* __restrict__ x, const float* __restrict__ g,
                                                 const float* __restrict__ b, u8* __restrict__ out) {
  const int row = blockIdx.x, tid = threadIdx.x;
  const float* xr = x + (size_t)row * 1024;
  float4 v = *(const float4*)&xr[tid * 4];
  float s = v.x + v.y + v.z + v.w;
  float s2 = v.x * v.x + v.y * v.y + v.z * v.z + v.w * v.w;
#pragma unroll
  for (int off = 32; off; off >>= 1) { s += __shfl_xor(s, off); s2 += __shfl_xor(s2, off); }
  __shared__ float ps[4], ps2[4];
  const int wave = tid >> 6;
  if ((tid & 63) == 0) { ps[wave] = s; ps2[wave] = s2; }
  __syncthreads();
  s = ps[0] + ps[1] + ps[2] + ps[3];
  s2 = ps2[0] + ps2[1] + ps2[2] + ps2[3];
  const float mu = s * (1.0f / 1024.0f);
  const float var = s2 * (1.0f / 1024.0f) - mu * mu;
  const float rs = rsqrtf(var + 1e-5f);
  float4 gv = *(const float4*)&g[tid * 4];
  float4 bv = *(const float4*)&b[tid * 4];
  uint32_t o = f2fp8x4((v.x - mu) * rs * gv.x + bv.x, (v.y - mu) * rs * gv.y + bv.y,
                       (v.z - mu) * rs * gv.z + bv.z, (v.w - mu) * rs * gv.w + bv.w);
  *(uint32_t*)&out[(size_t)row * 1024 + tid * 4] = o;
}

// ---------------------------------------------------------------- fp8 MX GEMM: C[M][N] = A[M][K] * Bt[N][K]^T
// 128x128 tile, BK=128, 4 waves (2x2), per-wave 64x64 via 32x32x64 f8f6f4 MFMA.
// LDS rows 128 B = 8 chunks of 16 B, phys_chunk = log_chunk ^ (row&7) (measured
// conflict-free this geometry). Staging: global_load_lds w/ inverse-swizzled src.
// A-frag: lane l = row l&31, k = 32*(l>>5)+j (linear bytes). C/D: col=l&31,
// row=(reg&3)+8*(reg>>2)+4*(l>>5).
// EPI 0: bf16 out = acc+bias (QKV); 1: outf = xres+ls*(acc+bias) (proj+res1);
// EPI 2: fp8 out = gelu(acc+bias) (FC1); 3: outf += ls*(acc+bias) (FC2+res2).
__device__ __forceinline__ i32x8 ld_frag8(const u8* S, int row, int kk, int lk, int sw) {
  const int c0 = kk * 4 + lk * 2;
  const u8* rp = S + row * 128;
  int4 lo = *(const int4*)(rp + ((c0 ^ sw) * 16));
  int4 hi = *(const int4*)(rp + (((c0 + 1) ^ sw) * 16));
  i32x8 r = {lo.x, lo.y, lo.z, lo.w, hi.x, hi.y, hi.z, hi.w};
  return r;
}

template <int EPI>
__global__ __launch_bounds__(256, 3) void gemm_f8(const u8* __restrict__ A, const u8* __restrict__ Bt,
                                                  const float* __restrict__ bias, const float* __restrict__ xres,
                                                  const float* __restrict__ ls, float* __restrict__ outf,
                                                  u16* __restrict__ outh, u8* __restrict__ out8,
                                                  int M, int N, int K) {
  __shared__ __attribute__((aligned(16))) u8 As[128 * 128];
  __shared__ __attribute__((aligned(16))) u8 Bs[128 * 128];
  const int tid = threadIdx.x;
  const int w = tid >> 6, l = tid & 63;
  const int wr = w >> 1, wc = w & 1;
  const int l31 = l & 31, lk = l >> 5, sw = l & 7;
  const int bm = blockIdx.x, bn = blockIdx.y;

  f32x16 acc[2][2];
#pragma unroll
  for (int mi = 0; mi < 2; mi++)
#pragma unroll
    for (int ni = 0; ni < 2; ni++)
#pragma unroll
      for (int r = 0; r < 16; r++) acc[mi][ni][r] = 0.f;

  // staging: thread covers dst row w*8+(l>>3) (+32 per issue), phys chunk l&7;
  // inverse swizzle on global source chunk
  const int srow = w * 8 + (l >> 3);
  const int schunk = ((l & 7) ^ (l >> 3)) * 16;
  const u8* Ag = A + (size_t)(bm * 128 + srow) * K + schunk;
  const u8* Bg = Bt + (size_t)(bn * 128 + srow) * K + schunk;
  u8* Asw = &As[w * 1024];
  u8* Bsw = &Bs[w * 1024];
  const size_t row32K = (size_t)32 * K;

  for (int kt = 0; kt < K; kt += 128) {
    __syncthreads();
#pragma unroll
    for (int i = 0; i < 4; i++) gl_lds16(Ag + i * row32K + kt, Asw + i * 4096);
#pragma unroll
    for (int i = 0; i < 4; i++) gl_lds16(Bg + i * row32K + kt, Bsw + i * 4096);
    __syncthreads();
#pragma unroll
    for (int kk = 0; kk < 2; kk++) {
      i32x8 af[2], bf[2];
#pragma unroll
      for (int mi = 0; mi < 2; mi++) af[mi] = ld_frag8(As, wr * 64 + mi * 32 + l31, kk, lk, sw);
#pragma unroll
      for (int ni = 0; ni < 2; ni++) bf[ni] = ld_frag8(Bs, wc * 64 + ni * 32 + l31, kk, lk, sw);
#pragma unroll
      for (int mi = 0; mi < 2; mi++)
#pragma unroll
        for (int ni = 0; ni < 2; ni++) acc[mi][ni] = MFMA_FP8(af[mi], bf[ni], acc[mi][ni]);
    }
  }

  const int row0 = bm * 128 + wr * 64 + lk * 4;
  const int col0 = bn * 128 + wc * 64 + l31;
#pragma unroll
  for (int mi = 0; mi < 2; mi++)
#pragma unroll
    for (int ni = 0; ni < 2; ni++)
#pragma unroll
      for (int reg = 0; reg < 16; reg++) {
        const int r = row0 + mi * 32 + (reg & 3) + 8 * (reg >> 2);
        const int c = col0 + ni * 32;
        float v = acc[mi][ni][reg];
        if constexpr (EPI == 0) {
          outh[(size_t)r * N + c] = f2bf(v + bias[c]);
        } else if constexpr (EPI == 1) {
          const size_t idx = (size_t)r * N + c;
          outf[idx] = xres[idx] + ls[c] * (v + bias[c]);
        } else if constexpr (EPI == 2) {
          v += bias[c];
          out8[(size_t)r * N + c] = f2fp8(0.5f * v * (1.0f + erff(v * 0.70710678118654752f)));
        } else {
          const size_t idx = (size_t)r * N + c;
          outf[idx] += ls[c] * (v + bias[c]);
        }
      }
}

// ---------------------------------------------------------------- flash attention (bf16, T2-swizzled LDS), fp8 output
__global__ __launch_bounds__(256, 3) void attn_kernel(const u16* __restrict__ qkv, const u16* __restrict__ vt,
                                                      u8* __restrict__ o) {
  __shared__ __attribute__((aligned(16))) u16 Ks[128 * 64];
  __shared__ __attribute__((aligned(16))) u16 Vs[64 * 128];
  __shared__ __attribute__((aligned(16))) u16 PQ[4 * 16 * 128];
  u16* Qs = PQ;
  const int tid = threadIdx.x;
  const int wave = tid >> 6, lane = tid & 63;
  const int lrow = lane & 15, lhi = lane >> 4;
  const int qt = blockIdx.x;
  const int bh = blockIdx.y;
  const int b = bh >> 4, h = bh & 15;
  const int swz8 = (lane & 7) ^ (lane >> 3);
  const int swz16 = (lane & 15) ^ (wave * 4 + (lane >> 4));

  {
    const u16* gq = qkv + (size_t)(b * 1024 + qt * 64 + wave * 8 + (lane >> 3)) * 3072 + h * 64 + swz8 * 8;
    gl_lds16(gq, &Qs[(wave * 8) * 64]);
    gl_lds16(gq + (size_t)32 * 3072, &Qs[(32 + wave * 8) * 64]);
  }
  __syncthreads();
  const int pq0 = (lhi ^ (lrow & 7)) * 8;
  bf16x8 qf0 = *(const bf16x8*)&Qs[(wave * 16 + lrow) * 64 + pq0];
  bf16x8 qf1 = *(const bf16x8*)&Qs[(wave * 16 + lrow) * 64 + (pq0 ^ 32)];

  float m_[4], l_[4];
  f32x4 oa[4];
  f32x4 zero = {0.f, 0.f, 0.f, 0.f};
#pragma unroll
  for (int i = 0; i < 4; i++) { m_[i] = -1e30f; l_[i] = 0.f; oa[i] = zero; }

  const u16* kg = qkv + (size_t)(b * 1024 + wave * 8 + (lane >> 3)) * 3072 + 1024 + h * 64 + swz8 * 8;
  const u16* vg = vt + (size_t)bh * 65536 + (size_t)(wave * 4 + (lane >> 4)) * 1024 + swz16 * 8;

  for (int kt = 0; kt < 1024; kt += 128) {
    __syncthreads();
#pragma unroll
    for (int i = 0; i < 4; i++) gl_lds16(kg + (size_t)(kt + i * 32) * 3072, &Ks[(i * 32 + wave * 8) * 64]);
#pragma unroll
    for (int i = 0; i < 4; i++) gl_lds16(vg + (size_t)(i * 16) * 1024 + kt, &Vs[(i * 16 + wave * 4) * 128]);
    __syncthreads();

    f32x4 sf[8];
#pragma unroll
    for (int n = 0; n < 8; n++) sf[n] = zero;
#pragma unroll
    for (int n = 0; n < 8; n++) {
      bf16x8 kf0 = *(const bf16x8*)&Ks[(n * 16 + lrow) * 64 + pq0];
      bf16x8 kf1 = *(const bf16x8*)&Ks[(n * 16 + lrow) * 64 + (pq0 ^ 32)];
      sf[n] = MFMA_BF16(qf0, kf0, sf[n]);
      sf[n] = MFMA_BF16(qf1, kf1, sf[n]);
    }

    float tm[4] = {-1e30f, -1e30f, -1e30f, -1e30f};
#pragma unroll
    for (int n = 0; n < 8; n++)
#pragma unroll
      for (int i = 0; i < 4; i++) tm[i] = fmaxf(tm[i], sf[n][i]);
#pragma unroll
    for (int i = 0; i < 4; i++) tm[i] *= 0.125f;
#pragma unroll
    for (int off = 1; off < 16; off <<= 1)
#pragma unroll
      for (int i = 0; i < 4; i++) tm[i] = fmaxf(tm[i], __shfl_xor(tm[i], off));
    float al[4];
#pragma unroll
    for (int i = 0; i < 4; i++) {
      const float mn = fmaxf(m_[i], tm[i]);
      al[i] = __expf(m_[i] - mn);
      m_[i] = mn;
    }
    float rs[4] = {0.f, 0.f, 0.f, 0.f};
#pragma unroll
    for (int n = 0; n < 8; n++)
#pragma unroll
      for (int i = 0; i < 4; i++) {
        const float p = __expf(sf[n][i] * 0.125f - m_[i]);
        rs[i] += p;
        const int q = lhi * 4 + i;
        PQ[wave * 2048 + q * 128 + (((n * 2 + (lrow >> 3)) ^ q) * 8) + (lrow & 7)] = f2bf(p);
      }
#pragma unroll
    for (int off = 1; off < 16; off <<= 1)
#pragma unroll
      for (int i = 0; i < 4; i++) rs[i] += __shfl_xor(rs[i], off);
#pragma unroll
    for (int i = 0; i < 4; i++) l_[i] = l_[i] * al[i] + rs[i];
#pragma unroll
    for (int n2 = 0; n2 < 4; n2++)
#pragma unroll
      for (int i = 0; i < 4; i++) oa[n2][i] *= al[i];

#pragma unroll
    for (int ks = 0; ks < 4; ks++) {
      bf16x8 pf = *(const bf16x8*)&PQ[wave * 2048 + lrow * 128 + (((ks * 4 + lhi) ^ lrow) * 8)];
#pragma unroll
      for (int n2 = 0; n2 < 4; n2++) {
        bf16x8 vf = *(const bf16x8*)&Vs[(n2 * 16 + lrow) * 128 + (((ks * 4 + lhi) ^ lrow) * 8)];
        oa[n2] = MFMA_BF16(pf, vf, oa[n2]);
      }
    }
  }

#pragma unroll
  for (int n2 = 0; n2 < 4; n2++)
#pragma unroll
    for (int i = 0; i < 4; i++) {
      const int tok = qt * 64 + wave * 16 + lhi * 4 + i;
      o[(size_t)(b * 1024 + tok) * 1024 + h * 64 + n2 * 16 + lrow] = f2fp8(oa[n2][i] / l_[i]);
    }
}

// ----------------------------------------------------------------
extern "C" void kernel_launch(void* const* d_in, const int* in_sizes, int n_in, void* d_out, int out_size,
                              void* d_ws, size_t ws_size, hipStream_t stream) {
  const float* x = (const float*)d_in[0];
  const float* ln1_g = (const float*)d_in[1];
  const float* ln1_b = (const float*)d_in[2];
  const float* qkv_w = (const float*)d_in[3];
  const float* qkv_b = (const float*)d_in[4];
  const float* proj_w = (const float*)d_in[5];
  const float* proj_b = (const float*)d_in[6];
  const float* ls1_g = (const float*)d_in[7];
  const float* ln2_g = (const float*)d_in[8];
  const float* ln2_b = (const float*)d_in[9];
  const float* fc1_w = (const float*)d_in[10];
  const float* fc1_b = (const float*)d_in[11];
  const float* fc2_w = (const float*)d_in[12];
  const float* fc2_b = (const float*)d_in[13];
  const float* ls2_g = (const float*)d_in[14];
  float* out = (float*)d_out;

  u8* p = (u8*)d_ws;
  u8* wq8 = p;  p += (size_t)3072 * 1024;
  u8* wp8 = p;  p += (size_t)1024 * 1024;
  u8* wf18 = p; p += (size_t)4096 * 1024;
  u8* wf28 = p; p += (size_t)1024 * 4096;
  u8* hbuf8 = p; p += (size_t)8192 * 1024;
  u16* qkvb = (u16*)p; p += (size_t)8192 * 3072 * 2;  // bf16 (attention input)
  u16* vtb = (u16*)p;  p += (size_t)128 * 64 * 1024 * 2;
  u8* ob8 = p;  p += (size_t)8192 * 1024;
  u8* hid8 = (u8*)qkvb;  // [8192][4096] fp8, aliases qkv+vtb region (dead by FC1)

  // weight transposes (fp32 -> fp8, [K][N] -> [N][K])
  transpose_conv8<<<dim3(96, 32), 256, 0, stream>>>(qkv_w, wq8, 1024, 3072);
  transpose_conv8<<<dim3(32, 32), 256, 0, stream>>>(proj_w, wp8, 1024, 1024);
  transpose_conv8<<<dim3(128, 32), 256, 0, stream>>>(fc1_w, wf18, 1024, 4096);
  transpose_conv8<<<dim3(32, 128), 256, 0, stream>>>(fc2_w, wf28, 4096, 1024);

  // LN1 (fp8 out)
  ln_kernel<<<8192, 256, 0, stream>>>(x, ln1_g, ln1_b, hbuf8);
  // QKV (fp8 MX -> bf16)
  gemm_f8<0><<<dim3(64, 24), 256, 0, stream>>>(hbuf8, wq8, qkv_b, nullptr, nullptr, nullptr, qkvb, nullptr,
                                               8192, 3072, 1024);
  // V^T extraction (bf16)
  transpose_v<<<dim3(2, 32, 128), 256, 0, stream>>>(qkvb, vtb);
  // attention (bf16 compute, fp8 out)
  attn_kernel<<<dim3(16, 128), 256, 0, stream>>>(qkvb, vtb, ob8);
  // proj + residual1 -> d_out (fp32)
  gemm_f8<1><<<dim3(64, 8), 256, 0, stream>>>(ob8, wp8, proj_b, x, ls1_g, out, nullptr, nullptr,
                                              8192, 1024, 1024);
  // LN2 (fp8 out)
  ln_kernel<<<8192, 256, 0, stream>>>(out, ln2_g, ln2_b, hbuf8);
  // FC1 + GELU (fp8 out)
  gemm_f8<2><<<dim3(64, 32), 256, 0, stream>>>(hbuf8, wf18, fc1_b, nullptr, nullptr, nullptr, nullptr, hid8,
                                               8192, 4096, 1024);
  // FC2 + residual2 (RMW on d_out)
  gemm_f8<3><<<dim3(64, 8), 256, 0, stream>>>(hid8, wf28, fc2_b, nullptr, ls2_g, out, nullptr, nullptr,
                                              8192, 1024, 4096);
}

// Round 5
// 284.740 us; speedup vs baseline: 1.5105x; 1.0636x over previous
//
#include <hip/hip_runtime.h>
#include <hip/hip_bf16.h>
#include <cstdint>

using u16 = unsigned short;
using u8 = unsigned char;
typedef __attribute__((ext_vector_type(8))) short bf16x8;
typedef __attribute__((ext_vector_type(4))) float f32x4;
typedef __attribute__((ext_vector_type(16))) float f32x16;
typedef __attribute__((ext_vector_type(8))) int i32x8;
typedef __attribute__((ext_vector_type(4))) u16 u16x4;

#define MFMA_BF16(a, b, c) __builtin_amdgcn_mfma_f32_16x16x32_bf16((a), (b), (c), 0, 0, 0)
// MX-scaled fp8 MFMA, unit scales (e8m0 0x7F = 2^0)
#define MFMA_FP8(a, b, c) \
  __builtin_amdgcn_mfma_scale_f32_32x32x64_f8f6f4((a), (b), (c), 0, 0, 0, 0x7f7f7f7f, 0, 0x7f7f7f7f)

__device__ __forceinline__ u16 f2bf(float f) {
  __hip_bfloat16 h = __float2bfloat16(f);
  return __builtin_bit_cast(u16, h);
}

__device__ __forceinline__ u8 f2fp8(float a) {
  int r = __builtin_amdgcn_cvt_pk_fp8_f32(a, a, 0, false);
  return (u8)(r & 0xff);
}

__device__ __forceinline__ uint32_t f2fp8x4(float a, float b, float c, float d) {
  int r = __builtin_amdgcn_cvt_pk_fp8_f32(a, b, 0, false);
  r = __builtin_amdgcn_cvt_pk_fp8_f32(c, d, r, true);
  return (uint32_t)r;
}

__device__ __forceinline__ void gl_lds16(const void* gsrc, void* ldst) {
  __builtin_amdgcn_global_load_lds(
      (__attribute__((address_space(1))) void*)const_cast<void*>(gsrc),
      (__attribute__((address_space(3))) void*)ldst, 16, 0, 0);
}

// ---------------------------------------------------------------- transpose+convert: src [K][N] f32 -> dst [N][K] fp8
__global__ __launch_bounds__(256) void transpose_conv8(const float* __restrict__ src,
                                                       u8* __restrict__ dst, int K, int N) {
  __shared__ float t[32][33];
  const int bx = blockIdx.x, by = blockIdx.y;  // bx: N/32, by: K/32
  const int tid = threadIdx.x;
  const int r = tid >> 3, c = (tid & 7) * 4;
  const float4 v = *(const float4*)&src[(size_t)(by * 32 + r) * N + bx * 32 + c];
  t[r][c] = v.x; t[r][c + 1] = v.y; t[r][c + 2] = v.z; t[r][c + 3] = v.w;
  __syncthreads();
  uint32_t o = f2fp8x4(t[c][r], t[c + 1][r], t[c + 2][r], t[c + 3][r]);
  *(uint32_t*)&dst[(size_t)(bx * 32 + r) * K + by * 32 + c] = o;
}

// ---------------------------------------------------------------- V^T extraction: qkv [8192][3072] bf16 -> vt [128][64][1024] bf16
__global__ __launch_bounds__(256) void transpose_v(const u16* __restrict__ qkv, u16* __restrict__ dst) {
  __shared__ u16 t[32][40];
  const int bx = blockIdx.x;  // d-block: 0..1
  const int by = blockIdx.y;  // n-block: 0..31
  const int bh = blockIdx.z;  // 0..127
  const int b = bh >> 4, h = bh & 15;
  const int tid = threadIdx.x;
  const int r = tid >> 3, c = (tid & 7) * 4;
  u16x4 v = *(const u16x4*)&qkv[(size_t)(b * 1024 + by * 32 + r) * 3072 + 2048 + h * 64 + bx * 32 + c];
  t[r][c] = v.x; t[r][c + 1] = v.y; t[r][c + 2] = v.z; t[r][c + 3] = v.w;
  __syncthreads();
  u16x4 o = {t[c][r], t[c + 1][r], t[c + 2][r], t[c + 3][r]};
  *(u16x4*)&dst[(size_t)bh * 65536 + (size_t)(bx * 32 + r) * 1024 + by * 32 + c] = o;
}

// ---------------------------------------------------------------- LayerNorm: x f32 [8192][1024] -> fp8 out
__global__ __launch_bounds__(256) void ln_kernel(const float* __restrict__ x, const float* __restrict__ g,
                                                 const float* __restrict__ b, u8* __restrict__ out) {
  const int row = blockIdx.x, tid = threadIdx.x;
  const float* xr = x + (size_t)row * 1024;
  float4 v = *(const float4*)&xr[tid * 4];
  float s = v.x + v.y + v.z + v.w;
  float s2 = v.x * v.x + v.y * v.y + v.z * v.z + v.w * v.w;
#pragma unroll
  for (int off = 32; off; off >>= 1) { s += __shfl_xor(s, off); s2 += __shfl_xor(s2, off); }
  __shared__ float ps[4], ps2[4];
  const int wave = tid >> 6;
  if ((tid & 63) == 0) { ps[wave] = s; ps2[wave] = s2; }
  __syncthreads();
  s = ps[0] + ps[1] + ps[2] + ps[3];
  s2 = ps2[0] + ps2[1] + ps2[2] + ps2[3];
  const float mu = s * (1.0f / 1024.0f);
  const float var = s2 * (1.0f / 1024.0f) - mu * mu;
  const float rs = rsqrtf(var + 1e-5f);
  float4 gv = *(const float4*)&g[tid * 4];
  float4 bv = *(const float4*)&b[tid * 4];
  uint32_t o = f2fp8x4((v.x - mu) * rs * gv.x + bv.x, (v.y - mu) * rs * gv.y + bv.y,
                       (v.z - mu) * rs * gv.z + bv.z, (v.w - mu) * rs * gv.w + bv.w);
  *(uint32_t*)&out[(size_t)row * 1024 + tid * 4] = o;
}

// ---------------------------------------------------------------- fp8 MX GEMM (unchanged from round 4)
__device__ __forceinline__ i32x8 ld_frag8(const u8* S, int row, int kk, int lk, int sw) {
  const int c0 = kk * 4 + lk * 2;
  const u8* rp = S + row * 128;
  int4 lo = *(const int4*)(rp + ((c0 ^ sw) * 16));
  int4 hi = *(const int4*)(rp + (((c0 + 1) ^ sw) * 16));
  i32x8 r = {lo.x, lo.y, lo.z, lo.w, hi.x, hi.y, hi.z, hi.w};
  return r;
}

template <int EPI>
__global__ __launch_bounds__(256, 3) void gemm_f8(const u8* __restrict__ A, const u8* __restrict__ Bt,
                                                  const float* __restrict__ bias, const float* __restrict__ xres,
                                                  const float* __restrict__ ls, float* __restrict__ outf,
                                                  u16* __restrict__ outh, u8* __restrict__ out8,
                                                  int M, int N, int K) {
  __shared__ __attribute__((aligned(16))) u8 As[128 * 128];
  __shared__ __attribute__((aligned(16))) u8 Bs[128 * 128];
  const int tid = threadIdx.x;
  const int w = tid >> 6, l = tid & 63;
  const int wr = w >> 1, wc = w & 1;
  const int l31 = l & 31, lk = l >> 5, sw = l & 7;
  const int bm = blockIdx.x, bn = blockIdx.y;

  f32x16 acc[2][2];
#pragma unroll
  for (int mi = 0; mi < 2; mi++)
#pragma unroll
    for (int ni = 0; ni < 2; ni++)
#pragma unroll
      for (int r = 0; r < 16; r++) acc[mi][ni][r] = 0.f;

  const int srow = w * 8 + (l >> 3);
  const int schunk = ((l & 7) ^ (l >> 3)) * 16;
  const u8* Ag = A + (size_t)(bm * 128 + srow) * K + schunk;
  const u8* Bg = Bt + (size_t)(bn * 128 + srow) * K + schunk;
  u8* Asw = &As[w * 1024];
  u8* Bsw = &Bs[w * 1024];
  const size_t row32K = (size_t)32 * K;

  for (int kt = 0; kt < K; kt += 128) {
    __syncthreads();
#pragma unroll
    for (int i = 0; i < 4; i++) gl_lds16(Ag + i * row32K + kt, Asw + i * 4096);
#pragma unroll
    for (int i = 0; i < 4; i++) gl_lds16(Bg + i * row32K + kt, Bsw + i * 4096);
    __syncthreads();
#pragma unroll
    for (int kk = 0; kk < 2; kk++) {
      i32x8 af[2], bf[2];
#pragma unroll
      for (int mi = 0; mi < 2; mi++) af[mi] = ld_frag8(As, wr * 64 + mi * 32 + l31, kk, lk, sw);
#pragma unroll
      for (int ni = 0; ni < 2; ni++) bf[ni] = ld_frag8(Bs, wc * 64 + ni * 32 + l31, kk, lk, sw);
#pragma unroll
      for (int mi = 0; mi < 2; mi++)
#pragma unroll
        for (int ni = 0; ni < 2; ni++) acc[mi][ni] = MFMA_FP8(af[mi], bf[ni], acc[mi][ni]);
    }
  }

  const int row0 = bm * 128 + wr * 64 + lk * 4;
  const int col0 = bn * 128 + wc * 64 + l31;
#pragma unroll
  for (int mi = 0; mi < 2; mi++)
#pragma unroll
    for (int ni = 0; ni < 2; ni++)
#pragma unroll
      for (int reg = 0; reg < 16; reg++) {
        const int r = row0 + mi * 32 + (reg & 3) + 8 * (reg >> 2);
        const int c = col0 + ni * 32;
        float v = acc[mi][ni][reg];
        if constexpr (EPI == 0) {
          outh[(size_t)r * N + c] = f2bf(v + bias[c]);
        } else if constexpr (EPI == 1) {
          const size_t idx = (size_t)r * N + c;
          outf[idx] = xres[idx] + ls[c] * (v + bias[c]);
        } else if constexpr (EPI == 2) {
          v += bias[c];
          out8[(size_t)r * N + c] = f2fp8(0.5f * v * (1.0f + erff(v * 0.70710678118654752f)));
        } else {
          const size_t idx = (size_t)r * N + c;
          outf[idx] += ls[c] * (v + bias[c]);
        }
      }
}

// ---------------------------------------------------------------- flash attention, swapped-QK^T row-local softmax
// S^T = mfma(K, Q): lane holds S[kv = n*16 + 4*lhi + i][q = lrow] -> row
// reductions are in-lane + 2 shfl. P written as b64 (4 bf16) with the same
// chunk-XOR swizzle key (chunk ^ q) the PV read uses. exp2-domain softmax,
// defer-max (THR=8 in log2 domain).
__global__ __launch_bounds__(256, 3) void attn_kernel(const u16* __restrict__ qkv, const u16* __restrict__ vt,
                                                      u8* __restrict__ o) {
  __shared__ __attribute__((aligned(16))) u16 Ks[128 * 64];
  __shared__ __attribute__((aligned(16))) u16 Vs[64 * 128];
  __shared__ __attribute__((aligned(16))) u16 PQ[4 * 16 * 128];
  u16* Qs = PQ;
  const int tid = threadIdx.x;
  const int wave = tid >> 6, lane = tid & 63;
  const int lrow = lane & 15, lhi = lane >> 4;
  const int qt = blockIdx.x;
  const int bh = blockIdx.y;
  const int b = bh >> 4, h = bh & 15;
  const int swz8 = (lane & 7) ^ (lane >> 3);
  const int swz16 = (lane & 15) ^ (wave * 4 + (lane >> 4));
  const float SC = 0.18033688011f;  // 0.125 * log2(e)

  {
    const u16* gq = qkv + (size_t)(b * 1024 + qt * 64 + wave * 8 + (lane >> 3)) * 3072 + h * 64 + swz8 * 8;
    gl_lds16(gq, &Qs[(wave * 8) * 64]);
    gl_lds16(gq + (size_t)32 * 3072, &Qs[(32 + wave * 8) * 64]);
  }
  __syncthreads();
  const int pq0 = (lhi ^ (lrow & 7)) * 8;
  bf16x8 qf0 = *(const bf16x8*)&Qs[(wave * 16 + lrow) * 64 + pq0];
  bf16x8 qf1 = *(const bf16x8*)&Qs[(wave * 16 + lrow) * 64 + (pq0 ^ 32)];

  float m_ = -1e30f, l_ = 0.f;  // for q = lrow, log2 domain
  f32x4 oa[4];                  // O[q = 4*lhi + i][d = n2*16 + lrow]
  f32x4 zero = {0.f, 0.f, 0.f, 0.f};
#pragma unroll
  for (int i = 0; i < 4; i++) oa[i] = zero;

  const u16* kg = qkv + (size_t)(b * 1024 + wave * 8 + (lane >> 3)) * 3072 + 1024 + h * 64 + swz8 * 8;
  const u16* vg = vt + (size_t)bh * 65536 + (size_t)(wave * 4 + (lane >> 4)) * 1024 + swz16 * 8;

  for (int kt = 0; kt < 1024; kt += 128) {
    __syncthreads();
#pragma unroll
    for (int i = 0; i < 4; i++) gl_lds16(kg + (size_t)(kt + i * 32) * 3072, &Ks[(i * 32 + wave * 8) * 64]);
#pragma unroll
    for (int i = 0; i < 4; i++) gl_lds16(vg + (size_t)(i * 16) * 1024 + kt, &Vs[(i * 16 + wave * 4) * 128]);
    __syncthreads();

    // S^T = K Q^T : sf[n][i] = S[kv = n*16 + 4*lhi + i][q = lrow]
    f32x4 sf[8];
#pragma unroll
    for (int n = 0; n < 8; n++) sf[n] = zero;
#pragma unroll
    for (int n = 0; n < 8; n++) {
      bf16x8 kf0 = *(const bf16x8*)&Ks[(n * 16 + lrow) * 64 + pq0];
      bf16x8 kf1 = *(const bf16x8*)&Ks[(n * 16 + lrow) * 64 + (pq0 ^ 32)];
      sf[n] = MFMA_BF16(kf0, qf0, sf[n]);
      sf[n] = MFMA_BF16(kf1, qf1, sf[n]);
    }

    // in-lane row max (32 values for q = lrow), then 2-shfl cross-group reduce
    float tn[8];
#pragma unroll
    for (int n = 0; n < 8; n++)
      tn[n] = fmaxf(fmaxf(sf[n][0], sf[n][1]), fmaxf(sf[n][2], sf[n][3]));
    float tm = fmaxf(fmaxf(fmaxf(tn[0], tn[1]), fmaxf(tn[2], tn[3])),
                     fmaxf(fmaxf(tn[4], tn[5]), fmaxf(tn[6], tn[7])));
    tm = fmaxf(tm, __shfl_xor(tm, 16));
    tm = fmaxf(tm, __shfl_xor(tm, 32));
    tm *= SC;  // log2 domain

    // defer-max: only rescale when the tile max grew past THR=8 (2^8 headroom)
    if (!__all(tm <= m_ + 8.0f)) {
      const float mn = fmaxf(m_, tm);
      const float al = exp2f(m_ - mn);
      m_ = mn;
      l_ *= al;
#pragma unroll
      for (int i = 0; i < 4; i++) {
        const float a = __shfl(al, lhi * 4 + i);
        oa[0][i] *= a; oa[1][i] *= a; oa[2][i] *= a; oa[3][i] *= a;
      }
    }

    // P = exp2(S*SC - m), packed b64 stores (4 consecutive kv per lane)
    float rsv[4] = {0.f, 0.f, 0.f, 0.f};
#pragma unroll
    for (int n = 0; n < 8; n++) {
      u16x4 pk;
#pragma unroll
      for (int i = 0; i < 4; i++) {
        const float p = exp2f(sf[n][i] * SC - m_);
        rsv[i] += p;
        pk[i] = f2bf(p);
      }
      const int c = 2 * n + (lhi >> 1);  // logical 8-elem chunk of kv
      *(u16x4*)&PQ[wave * 2048 + lrow * 128 + ((c ^ lrow) * 8) + (lhi & 1) * 4] = pk;
    }
    float rs = (rsv[0] + rsv[1]) + (rsv[2] + rsv[3]);
    rs += __shfl_xor(rs, 16);
    rs += __shfl_xor(rs, 32);
    l_ += rs;

    // O += P V  (P: [16][128] swizzled, V^T: [64][128] swizzled)
#pragma unroll
    for (int ks = 0; ks < 4; ks++) {
      bf16x8 pf = *(const bf16x8*)&PQ[wave * 2048 + lrow * 128 + (((ks * 4 + lhi) ^ lrow) * 8)];
#pragma unroll
      for (int n2 = 0; n2 < 4; n2++) {
        bf16x8 vf = *(const bf16x8*)&Vs[(n2 * 16 + lrow) * 128 + (((ks * 4 + lhi) ^ lrow) * 8)];
        oa[n2] = MFMA_BF16(pf, vf, oa[n2]);
      }
    }
  }

  float lq[4];
#pragma unroll
  for (int i = 0; i < 4; i++) lq[i] = 1.0f / __shfl(l_, lhi * 4 + i);
#pragma unroll
  for (int n2 = 0; n2 < 4; n2++)
#pragma unroll
    for (int i = 0; i < 4; i++) {
      const int tok = qt * 64 + wave * 16 + lhi * 4 + i;
      o[(size_t)(b * 1024 + tok) * 1024 + h * 64 + n2 * 16 + lrow] = f2fp8(oa[n2][i] * lq[i]);
    }
}

// ----------------------------------------------------------------
extern "C" void kernel_launch(void* const* d_in, const int* in_sizes, int n_in, void* d_out, int out_size,
                              void* d_ws, size_t ws_size, hipStream_t stream) {
  const float* x = (const float*)d_in[0];
  const float* ln1_g = (const float*)d_in[1];
  const float* ln1_b = (const float*)d_in[2];
  const float* qkv_w = (const float*)d_in[3];
  const float* qkv_b = (const float*)d_in[4];
  const float* proj_w = (const float*)d_in[5];
  const float* proj_b = (const float*)d_in[6];
  const float* ls1_g = (const float*)d_in[7];
  const float* ln2_g = (const float*)d_in[8];
  const float* ln2_b = (const float*)d_in[9];
  const float* fc1_w = (const float*)d_in[10];
  const float* fc1_b = (const float*)d_in[11];
  const float* fc2_w = (const float*)d_in[12];
  const float* fc2_b = (const float*)d_in[13];
  const float* ls2_g = (const float*)d_in[14];
  float* out = (float*)d_out;

  u8* p = (u8*)d_ws;
  u8* wq8 = p;  p += (size_t)3072 * 1024;
  u8* wp8 = p;  p += (size_t)1024 * 1024;
  u8* wf18 = p; p += (size_t)4096 * 1024;
  u8* wf28 = p; p += (size_t)1024 * 4096;
  u8* hbuf8 = p; p += (size_t)8192 * 1024;
  u16* qkvb = (u16*)p; p += (size_t)8192 * 3072 * 2;  // bf16 (attention input)
  u16* vtb = (u16*)p;  p += (size_t)128 * 64 * 1024 * 2;
  u8* ob8 = p;  p += (size_t)8192 * 1024;
  u8* hid8 = (u8*)qkvb;  // [8192][4096] fp8, aliases qkv+vtb region (dead by FC1)

  // weight transposes (fp32 -> fp8, [K][N] -> [N][K])
  transpose_conv8<<<dim3(96, 32), 256, 0, stream>>>(qkv_w, wq8, 1024, 3072);
  transpose_conv8<<<dim3(32, 32), 256, 0, stream>>>(proj_w, wp8, 1024, 1024);
  transpose_conv8<<<dim3(128, 32), 256, 0, stream>>>(fc1_w, wf18, 1024, 4096);
  transpose_conv8<<<dim3(32, 128), 256, 0, stream>>>(fc2_w, wf28, 4096, 1024);

  // LN1 (fp8 out)
  ln_kernel<<<8192, 256, 0, stream>>>(x, ln1_g, ln1_b, hbuf8);
  // QKV (fp8 MX -> bf16)
  gemm_f8<0><<<dim3(64, 24), 256, 0, stream>>>(hbuf8, wq8, qkv_b, nullptr, nullptr, nullptr, qkvb, nullptr,
                                               8192, 3072, 1024);
  // V^T extraction (bf16)
  transpose_v<<<dim3(2, 32, 128), 256, 0, stream>>>(qkvb, vtb);
  // attention (bf16 compute, fp8 out)
  attn_kernel<<<dim3(16, 128), 256, 0, stream>>>(qkvb, vtb, ob8);
  // proj + residual1 -> d_out (fp32)
  gemm_f8<1><<<dim3(64, 8), 256, 0, stream>>>(ob8, wp8, proj_b, x, ls1_g, out, nullptr, nullptr,
                                              8192, 1024, 1024);
  // LN2 (fp8 out)
  ln_kernel<<<8192, 256, 0, stream>>>(out, ln2_g, ln2_b, hbuf8);
  // FC1 + GELU (fp8 out)
  gemm_f8<2><<<dim3(64, 32), 256, 0, stream>>>(hbuf8, wf18, fc1_b, nullptr, nullptr, nullptr, nullptr, hid8,
                                               8192, 4096, 1024);
  // FC2 + residual2 (RMW on d_out)
  gemm_f8<3><<<dim3(64, 8), 256, 0, stream>>>(hid8, wf28, fc2_b, nullptr, ls2_g, out, nullptr, nullptr,
                                              8192, 1024, 4096);
}